// Round 24
// baseline (183.621 us; speedup 1.0000x reference)
//
#include <hip/hip_runtime.h>
#include <hip/hip_bf16.h>

// FraudSNN fused kernel: GEMM (bf16 MFMA) + LIF recurrence, T=10, F=256, H=512.
// R24: occupancy lever on the R19/R21 frame. 174us kernel runs 8 waves/CU (2/SIMD,
// 22% occ) -> VALUBusy 33% = SIMDs starved. Same frame at 1024 threads: 16 waves
// (4/SIMD), wave owns 32 rows x 32 h (acc[2][2]=16 regs, live ~58 < the 64-VGPR
// budget 1024-thr blocks get; R7 proved spill-free at 60). mem1 4 planes LDS 64KB,
// xt parity-dbuf, cur2[10][32][17]; 1 barrier/t, deferred LIF2. W1s cache dropped
// (R23: 25% W1-L2 cut = only 2us, not the wall).

typedef short short8 __attribute__((ext_vector_type(8)));
typedef float f32x4 __attribute__((ext_vector_type(4)));

__device__ __forceinline__ unsigned short bfbits(float f) {
  union { __hip_bfloat16 h; unsigned short u; } c;
  c.h = __float2bfloat16(f);   // hardware RNE
  return c.u;
}

__device__ __forceinline__ unsigned int bfpack(float a, float b) {
  return (unsigned int)bfbits(a) | ((unsigned int)bfbits(b) << 16);
}

__device__ __forceinline__ float fast_sigmoid(float z) {
  float e = __expf(-z);
  return __builtin_amdgcn_rcpf(1.0f + e);
}

__device__ __forceinline__ void lif4(f32x4& mv, const f32x4 av, float w2c, float pr[4]) {
#pragma unroll
  for (int e = 0; e < 4; ++e) {
    float m   = fmaf(mv[e], 0.9f, av[e]);     // beta*mem + cur1
    float spk = fast_sigmoid(fmaf(m, 10.f, -10.f));
    mv[e] = m - spk;
    pr[e] = fmaf(spk, w2c, pr[e]);
  }
}

__global__ void w1_to_bf16(const float* __restrict__ w1, unsigned short* __restrict__ o) {
  int i = blockIdx.x * 256 + threadIdx.x;      // 32768 float4s
  float4 v = reinterpret_cast<const float4*>(w1)[i];
  reinterpret_cast<uint2*>(o)[i] = make_uint2(bfpack(v.x, v.y), bfpack(v.z, v.w));
}

__device__ __forceinline__ short8 cvt_frag(const float* p) {
  const float4 v0 = *reinterpret_cast<const float4*>(p);
  const float4 v1 = *reinterpret_cast<const float4*>(p + 4);
  union { unsigned int u[4]; short8 s; } cv;
  cv.u[0] = bfpack(v0.x, v0.y);
  cv.u[1] = bfpack(v0.z, v0.w);
  cv.u[2] = bfpack(v1.x, v1.y);
  cv.u[3] = bfpack(v1.z, v1.w);
  return cv.s;
}

// 1024 threads = 16 waves. Block: 32 batch rows; wave w owns 32 rows x h in [w*32, w*32+32).
template <bool USE_WS>
__global__
__attribute__((amdgpu_flat_work_group_size(1024, 1024)))
void snn_main(const float* __restrict__ x,
              const unsigned short* __restrict__ w1bf,  // bf16 W1 (if USE_WS)
              const float* __restrict__ w1f,            // fp32 W1 (fallback)
              const float* __restrict__ b1,
              const float* __restrict__ w2,
              const float* __restrict__ b2,
              float* __restrict__ out)
{
  __shared__ __align__(16) float mem_lds[4][1024][4];         // 65,536 B, 0-conflict slots
  __shared__ __align__(16) unsigned short xt[2][2][32][132];  // [par][half][row][col] 33,792 B
  __shared__ float cur2_lds[10][32][17];                      // [t][row][wave] 21,760 B
                                                              // total 121,088 B

  const int tid  = threadIdx.x;
  const int lane = tid & 63;
  const int wave = tid >> 6;          // 0..15
  const int l15  = lane & 15;
  const int lq   = lane >> 4;         // 0..3
  const long b0  = (long)blockIdx.x * 32;
  const int h0   = wave * 32;         // 2 col-tiles of 16 per wave

  float w2l[2], b1l[2];
#pragma unroll
  for (int c = 0; c < 2; ++c) {
    int h = h0 + c * 16 + l15;
    w2l[c] = w2[h];
    b1l[c] = b1[h];
  }

#pragma unroll
  for (int p = 0; p < 4; ++p) {
    f32x4 z = {0.f, 0.f, 0.f, 0.f};
    *reinterpret_cast<f32x4*>(&mem_lds[p][tid][0]) = z;
  }

  // staging: thread -> row sr (0..31), f4 col sc (0..31); 2 float4 per t (one per half)
  const int sr = tid >> 5;
  const int sc = tid & 31;
  const float* xrow = x + (b0 + sr) * 2560;

  const unsigned short* wb = w1bf + (h0 + l15) * 256 + lq * 8;
  const float*          wf = w1f  + (h0 + l15) * 256 + lq * 8;

  // prologue: load+pack t=0 (pf = 2 uint2 = 4 VGPR)
  uint2 pf[2];
  {
    const float4 v0 = *reinterpret_cast<const float4*>(xrow + sc * 4);
    const float4 v1 = *reinterpret_cast<const float4*>(xrow + 128 + sc * 4);
    pf[0] = make_uint2(bfpack(v0.x, v0.y), bfpack(v0.z, v0.w));
    pf[1] = make_uint2(bfpack(v1.x, v1.y), bfpack(v1.z, v1.w));
  }

#pragma unroll 1
  for (int t = 0; t < 10; ++t) {
    const int par = t & 1;
    // ---- A: write pf(t) -> xt[par]; issue+pack loads for t+1 (full-phase cover).
    //      xt[par] was last read at compute(t-2); bar(t-1) separates -> safe. ----
    *reinterpret_cast<uint2*>(&xt[par][0][sr][sc * 4]) = pf[0];
    *reinterpret_cast<uint2*>(&xt[par][1][sr][sc * 4]) = pf[1];
    {
      const int tn = (t < 9) ? t + 1 : 9;   // tail: harmless re-read
      const float4 v0 = *reinterpret_cast<const float4*>(xrow + tn * 256 + sc * 4);
      const float4 v1 = *reinterpret_cast<const float4*>(xrow + tn * 256 + 128 + sc * 4);
      pf[0] = make_uint2(bfpack(v0.x, v0.y), bfpack(v0.z, v0.w));
      pf[1] = make_uint2(bfpack(v1.x, v1.y), bfpack(v1.z, v1.w));
    }
    __syncthreads();   // the ONLY per-t barrier: xt[par] visible

    // ---- GEMM: acc[2][2] = 16 regs, 4 MFMA per kk; 16 waves give the TLP ----
    f32x4 acc[2][2];
#pragma unroll
    for (int rt = 0; rt < 2; ++rt)
#pragma unroll
      for (int c = 0; c < 2; ++c) {
        f32x4 cc = { b1l[c], b1l[c], b1l[c], b1l[c] };
        acc[rt][c] = cc;
      }

    __builtin_amdgcn_s_setprio(1);
#pragma unroll
    for (int kk = 0; kk < 8; ++kk) {
      short8 a[2], bfr[2];
#pragma unroll
      for (int rt = 0; rt < 2; ++rt)
        a[rt] = *reinterpret_cast<const short8*>(
            &xt[par][kk >> 2][rt * 16 + l15][(kk & 3) * 32 + lq * 8]);
#pragma unroll
      for (int c = 0; c < 2; ++c) {
        if constexpr (USE_WS)
          bfr[c] = *reinterpret_cast<const short8*>(wb + c * 4096 + kk * 32);
        else
          bfr[c] = cvt_frag(wf + c * 4096 + kk * 32);
      }
#pragma unroll
      for (int rt = 0; rt < 2; ++rt)
#pragma unroll
        for (int c = 0; c < 2; ++c)
          acc[rt][c] = __builtin_amdgcn_mfma_f32_16x16x32_bf16(a[rt], bfr[c], acc[rt][c], 0, 0, 0);
    }
    __builtin_amdgcn_s_setprio(0);

    // ---- LIF1 + partial W2 dot; 4 planes, all LDS own-slot ----
#pragma unroll
    for (int rt = 0; rt < 2; ++rt) {
      float pr[4] = {0.f, 0.f, 0.f, 0.f};
#pragma unroll
      for (int c = 0; c < 2; ++c) {
        const int p = rt * 2 + c;
        f32x4* slot = reinterpret_cast<f32x4*>(&mem_lds[p][tid][0]);
        f32x4 mv = *slot;
        lif4(mv, acc[rt][c], w2l[c], pr);
        *slot = mv;
      }
#pragma unroll
      for (int e = 0; e < 4; ++e) {
        float v = pr[e];
        v += __shfl_xor(v, 1); v += __shfl_xor(v, 2);
        v += __shfl_xor(v, 4); v += __shfl_xor(v, 8);
        if (l15 == 0) cur2_lds[t][rt * 16 + lq * 4 + e][wave] = v;
      }
    }
    // no second barrier: cur2_lds[t] is not read until after the final barrier
  }

  __syncthreads();   // final: all cur2 partials visible

  // ---- deferred LIF2: 10-step chain, once, on 32 threads ----
  if (tid < 32) {
    const float bias2 = b2[0];
    float mem2 = 0.f, spksum = 0.f;
#pragma unroll
    for (int t = 0; t < 10; ++t) {
      float c2 = bias2;
#pragma unroll
      for (int w = 0; w < 16; ++w) c2 += cur2_lds[t][tid][w];
      float m   = fmaf(mem2, 0.9f, c2);
      float spk = fast_sigmoid(fmaf(m, 10.f, -10.f));
      mem2   = m - spk;
      spksum += spk;
    }
    out[b0 + tid] = fast_sigmoid(spksum * 0.1f);   // FLOAT32 output
  }
}

extern "C" void kernel_launch(void* const* d_in, const int* in_sizes, int n_in,
                              void* d_out, int out_size, void* d_ws, size_t ws_size,
                              hipStream_t stream) {
  const float* x  = (const float*)d_in[0];
  const float* W1 = (const float*)d_in[1];
  const float* b1 = (const float*)d_in[2];
  const float* W2 = (const float*)d_in[3];
  const float* b2 = (const float*)d_in[4];
  float* out = (float*)d_out;
  (void)in_sizes; (void)n_in;

  const int grid = out_size / 32;   // out_size == B == 32768 -> 1024 blocks

  if (ws_size >= 512 * 256 * sizeof(unsigned short)) {
    unsigned short* w1bf = (unsigned short*)d_ws;   // 256 KB
    w1_to_bf16<<<128, 256, 0, stream>>>(W1, w1bf);
    snn_main<true><<<grid, 1024, 0, stream>>>(x, w1bf, W1, b1, W2, b2, out);
  } else {
    snn_main<false><<<grid, 1024, 0, stream>>>(x, nullptr, W1, b1, W2, b2, out);
  }
}